// Round 1
// baseline (674.208 us; speedup 1.0000x reference)
//
#include <hip/hip_runtime.h>
#include <cstdint>
#include <cstddef>

typedef unsigned int u32;
typedef unsigned short u16;
typedef __bf16 bf16x8 __attribute__((ext_vector_type(8)));
typedef float f32x4 __attribute__((ext_vector_type(4)));
typedef u16 u16x8 __attribute__((ext_vector_type(8)));

// Problem constants (fixed by the reference)
static constexpr int T_TOK = 4096;
static constexpr int HID   = 2048;
static constexpr int INTER = 1024;
static constexpr int NEXP  = 8;
static constexpr int TOPK  = 2;
static constexpr int SLOT_CAP = 9216;   // 8192 real slots + per-expert 128-align pad

// meta layout (ints): [0..7] counts, [8..15] offsets, [16] total_aligned,
// [17..24] cursors, [32..32+9216) toklist, [32+9216 .. +8192) slot_of
static constexpr int META_TOK = 32;
static constexpr int META_SLOTOF = 32 + SLOT_CAP;

__device__ __forceinline__ u16 f2bf(float f) {
  u32 u = __builtin_bit_cast(u32, f);
  u32 r = (u + 0x7fffu + ((u >> 16) & 1u)) >> 16;
  return (u16)r;
}
__device__ __forceinline__ float bf2f(u16 h) {
  return __builtin_bit_cast(float, (u32)h << 16);
}

// ---------------- router ----------------
__global__ void router_count(const int* __restrict__ eidx, int* __restrict__ meta) {
  __shared__ int cnt[NEXP];
  const int tid = threadIdx.x;
  if (tid < NEXP) cnt[tid] = 0;
  __syncthreads();
  for (int i = tid; i < T_TOK * TOPK; i += 256) atomicAdd(&cnt[eidx[i]], 1);
  __syncthreads();
  if (tid == 0) {
    int off = 0;
    for (int e = 0; e < NEXP; ++e) {
      int c = cnt[e];
      meta[e] = c;
      meta[8 + e] = off;
      meta[17 + e] = off;            // cursor starts at offset
      off += (c + 127) & ~127;       // 128-aligned region per expert
    }
    meta[16] = off;                  // total aligned slots
  }
}

__global__ void toklist_init(int* __restrict__ meta) {
  const int i = blockIdx.x * 256 + threadIdx.x;
  if (i < SLOT_CAP) meta[META_TOK + i] = 0;   // pad rows use token 0 (valid data, never combined)
}

__global__ void router_assign(const int* __restrict__ eidx, int* __restrict__ meta) {
  const int t = blockIdx.x * 256 + threadIdx.x;
  if (t >= T_TOK) return;
  int* cursors = meta + 17;
  int* toklist = meta + META_TOK;
  int* slot_of = meta + META_SLOTOF;
  for (int k = 0; k < TOPK; ++k) {
    const int e = eidx[t * TOPK + k];
    const int pos = atomicAdd(&cursors[e], 1);
    toklist[pos] = t;
    slot_of[t * TOPK + k] = pos;
  }
}

// ---------------- dequant / cast ----------------
// One thread = 4 packed int32 (4 bytes of nibbles) = 8 output bf16. CPR = chunks per row.
template <int CPR>
__global__ void dequant_k(const int* __restrict__ p, const float* __restrict__ s,
                          u16* __restrict__ w) {
  const int gid = blockIdx.x * 256 + threadIdx.x;
  const int row = gid / CPR;
  const int cid = gid % CPR;
  const int4 pk = *(const int4*)(p + (size_t)gid * 4);
  const float sc = s[(size_t)row * (CPR / 4) + (cid >> 2)];
  int v[4] = {pk.x, pk.y, pk.z, pk.w};
  u16x8 o;
#pragma unroll
  for (int b = 0; b < 4; ++b) {
    o[2 * b]     = f2bf((float)((v[b] & 15) - 8) * sc);
    o[2 * b + 1] = f2bf((float)(((v[b] >> 4) & 15) - 8) * sc);
  }
  *(u16x8*)(w + (size_t)gid * 8) = o;
}

__global__ void cast_x_k(const float* __restrict__ x, u16* __restrict__ xb) {
  const int i = (blockIdx.x * 256 + threadIdx.x) * 8;
  const float4 a = *(const float4*)(x + i);
  const float4 b = *(const float4*)(x + i + 4);
  u16x8 o;
  o[0] = f2bf(a.x); o[1] = f2bf(a.y); o[2] = f2bf(a.z); o[3] = f2bf(a.w);
  o[4] = f2bf(b.x); o[5] = f2bf(b.y); o[6] = f2bf(b.z); o[7] = f2bf(b.w);
  *(u16x8*)(xb + i) = o;
}

// ---------------- grouped GEMM ----------------
// C[slot, n] = sum_k A[row(slot), k] * B[n, k]   (B is K-major / B^T layout)
// 128x128 tile, BK=64, 4 waves (2x2 of 64x64), mfma 16x16x32 bf16.
template <int KT, bool GATHER>
__global__ __launch_bounds__(256) void gemm_tile(const u16* __restrict__ A,
                                                 const u16* __restrict__ B,
                                                 u16* __restrict__ C,
                                                 const int* __restrict__ meta) {
  const int e = blockIdx.x >> 5;
  const int mt = blockIdx.x & 31;
  const int cnt = meta[e];
  if (mt * 128 >= cnt) return;
  const int slot0 = meta[8 + e] + mt * 128;
  const int n0 = blockIdx.y * 128;
  const int tid = threadIdx.x;

  __shared__ u16 As[128 * 64];
  __shared__ u16 Bs[128 * 64];

  const u16* Be = B + (size_t)e * 2048 * KT;
  const int* toklist = meta + META_TOK;

  // staging sources: chunk c = j*256+tid covers 16B; row = c>>3, col-chunk = tid&7
  const int cofs = (tid & 7) * 8;
  const u16* asrc[4];
  const u16* bsrc[4];
#pragma unroll
  for (int j = 0; j < 4; ++j) {
    const int r = j * 32 + (tid >> 3);
    const int arow = GATHER ? toklist[slot0 + r] : (slot0 + r);
    asrc[j] = A + (size_t)arow * KT + cofs;
    bsrc[j] = Be + (size_t)(n0 + r) * KT + cofs;
  }

  f32x4 acc[4][4];
#pragma unroll
  for (int m = 0; m < 4; ++m)
#pragma unroll
    for (int n = 0; n < 4; ++n) acc[m][n] = (f32x4)0.0f;

  const int lane = tid & 63;
  const int wid = tid >> 6;
  const int wm = (wid >> 1) * 64;
  const int wn = (wid & 1) * 64;
  const int fr = lane & 15;
  const int fk = (lane >> 4) * 8;

  char* AsB = (char*)As;
  char* BsB = (char*)Bs;
  const int ldsoff = tid * 16;

  for (int kk = 0; kk < KT; kk += 64) {
    __syncthreads();
#pragma unroll
    for (int j = 0; j < 4; ++j) {
      __builtin_amdgcn_global_load_lds(
          (const __attribute__((address_space(1))) void*)(asrc[j] + kk),
          (__attribute__((address_space(3))) void*)(AsB + j * 4096 + ldsoff), 16, 0, 0);
      __builtin_amdgcn_global_load_lds(
          (const __attribute__((address_space(1))) void*)(bsrc[j] + kk),
          (__attribute__((address_space(3))) void*)(BsB + j * 4096 + ldsoff), 16, 0, 0);
    }
    __syncthreads();
#pragma unroll
    for (int ks = 0; ks < 2; ++ks) {
      bf16x8 a[4], b[4];
#pragma unroll
      for (int m = 0; m < 4; ++m)
        a[m] = *(const bf16x8*)&As[(wm + m * 16 + fr) * 64 + ks * 32 + fk];
#pragma unroll
      for (int n = 0; n < 4; ++n)
        b[n] = *(const bf16x8*)&Bs[(wn + n * 16 + fr) * 64 + ks * 32 + fk];
#pragma unroll
      for (int m = 0; m < 4; ++m)
#pragma unroll
        for (int n = 0; n < 4; ++n)
          acc[m][n] = __builtin_amdgcn_mfma_f32_16x16x32_bf16(a[m], b[n], acc[m][n], 0, 0, 0);
    }
  }

  // epilogue: C/D layout col=lane&15, row=(lane>>4)*4+j  [m89-verified]
  const int cr = (lane >> 4) * 4;
#pragma unroll
  for (int m = 0; m < 4; ++m)
#pragma unroll
    for (int n = 0; n < 4; ++n)
#pragma unroll
      for (int j = 0; j < 4; ++j) {
        const int row = slot0 + wm + m * 16 + cr + j;
        const int col = n0 + wn + n * 16 + fr;
        C[(size_t)row * 2048 + col] = f2bf(acc[m][n][j]);
      }
}

// ---------------- silu ----------------
__global__ void silu_k(const u16* __restrict__ y13, u16* __restrict__ h,
                       const int* __restrict__ meta) {
  const int idx = blockIdx.x * 256 + threadIdx.x;   // SLOT_CAP * (INTER/8)
  const int slot = idx >> 7;
  if (slot >= meta[16]) return;
  const int pos = (idx & 127) * 8;
  u16x8 g8 = *(const u16x8*)(y13 + (size_t)slot * 2048 + pos);
  u16x8 u8 = *(const u16x8*)(y13 + (size_t)slot * 2048 + 1024 + pos);
  u16x8 o;
#pragma unroll
  for (int j = 0; j < 8; ++j) {
    const float g = bf2f(g8[j]);
    const float u = bf2f(u8[j]);
    const float sg = g / (1.0f + __expf(-g));
    o[j] = f2bf(sg * u);
  }
  *(u16x8*)(h + (size_t)slot * 1024 + pos) = o;
}

// ---------------- combine ----------------
__global__ void combine_k(const u16* __restrict__ yp, const float* __restrict__ ew,
                          const int* __restrict__ meta, float* __restrict__ out) {
  const int idx = blockIdx.x * 256 + threadIdx.x;   // T * (HID/8)
  const int t = idx >> 8;
  const int pos = (idx & 255) * 8;
  const int* slot_of = meta + META_SLOTOF;
  const int s0 = slot_of[t * 2];
  const int s1 = slot_of[t * 2 + 1];
  const float w0 = ew[t * 2];
  const float w1 = ew[t * 2 + 1];
  const u16x8 v0 = *(const u16x8*)(yp + (size_t)s0 * 2048 + pos);
  const u16x8 v1 = *(const u16x8*)(yp + (size_t)s1 * 2048 + pos);
  float* dst = out + (size_t)t * 2048 + pos;
  float4 o0, o1;
  o0.x = w0 * bf2f(v0[0]) + w1 * bf2f(v1[0]);
  o0.y = w0 * bf2f(v0[1]) + w1 * bf2f(v1[1]);
  o0.z = w0 * bf2f(v0[2]) + w1 * bf2f(v1[2]);
  o0.w = w0 * bf2f(v0[3]) + w1 * bf2f(v1[3]);
  o1.x = w0 * bf2f(v0[4]) + w1 * bf2f(v1[4]);
  o1.y = w0 * bf2f(v0[5]) + w1 * bf2f(v1[5]);
  o1.z = w0 * bf2f(v0[6]) + w1 * bf2f(v1[6]);
  o1.w = w0 * bf2f(v0[7]) + w1 * bf2f(v1[7]);
  *(float4*)dst = o0;
  *(float4*)(dst + 4) = o1;
}

// ---------------- launch ----------------
extern "C" void kernel_launch(void* const* d_in, const int* in_sizes, int n_in,
                              void* d_out, int out_size, void* d_ws, size_t ws_size,
                              hipStream_t stream) {
  const float* x    = (const float*)d_in[0];
  const int*   w1   = (const int*)d_in[1];
  const float* w1s  = (const float*)d_in[2];
  const int*   w2   = (const int*)d_in[3];
  const float* w2s  = (const float*)d_in[4];
  const float* ew   = (const float*)d_in[5];
  const int*   eidx = (const int*)d_in[6];
  float* out = (float*)d_out;

  char* ws = (char*)d_ws;
  // ws layout (bytes)
  const size_t OFF_W1B  = 0;           // 8*2048*2048*2  = 67,108,864
  const size_t OFF_W2B  = 67108864;    // 8*2048*1024*2  = 33,554,432
  const size_t OFF_XB   = 100663296;   // 4096*2048*2    = 16,777,216
  const size_t OFF_Y13  = 117440512;   // 9216*2048*2    = 37,748,736 (also yp, reused)
  const size_t OFF_H    = 155189248;   // 9216*1024*2    = 18,874,368
  const size_t OFF_META = 174063616;   // 17440*4        = 69,760
  const size_t NEED     = 174133376;
  if (ws_size < NEED) return;

  u16* W1b  = (u16*)(ws + OFF_W1B);
  u16* W2b  = (u16*)(ws + OFF_W2B);
  u16* xb   = (u16*)(ws + OFF_XB);
  u16* y13  = (u16*)(ws + OFF_Y13);
  u16* hbuf = (u16*)(ws + OFF_H);
  int* meta = (int*)(ws + OFF_META);

  router_count<<<1, 256, 0, stream>>>(eidx, meta);
  toklist_init<<<SLOT_CAP / 256, 256, 0, stream>>>(meta);
  router_assign<<<T_TOK / 256, 256, 0, stream>>>(eidx, meta);

  cast_x_k<<<(T_TOK * HID) / (256 * 8), 256, 0, stream>>>(x, xb);
  // w1: rows = 8*2048 = 16384, chunks/row = (HID/2)/4 = 256
  dequant_k<256><<<16384 * 256 / 256, 256, 0, stream>>>(w1, w1s, W1b);
  // w2: rows = 8*2048 = 16384, chunks/row = (INTER/2)/4 = 128
  dequant_k<128><<<16384 * 128 / 256, 256, 0, stream>>>(w2, w2s, W2b);

  // GEMM1: y13[slot, 0..2048) = x[tok] . W1^T   (K=2048, gather rows)
  gemm_tile<2048, true><<<dim3(NEXP * 32, 16), 256, 0, stream>>>(xb, W1b, y13, meta);
  silu_k<<<SLOT_CAP * (INTER / 8) / 256, 256, 0, stream>>>(y13, hbuf, meta);
  // GEMM2: yp[slot, 0..2048) = h[slot] . W2^T   (K=1024, contiguous rows); yp aliases y13
  gemm_tile<1024, false><<<dim3(NEXP * 32, 16), 256, 0, stream>>>(hbuf, W2b, y13, meta);

  combine_k<<<(T_TOK * HID) / (256 * 8), 256, 0, stream>>>(y13, ew, meta, out);
}

// Round 2
// 326.471 us; speedup vs baseline: 2.0651x; 2.0651x over previous
//
#include <hip/hip_runtime.h>
#include <cstdint>
#include <cstddef>

typedef unsigned int u32;
typedef unsigned short u16;
typedef __bf16 bf16x8 __attribute__((ext_vector_type(8)));
typedef float f32x4 __attribute__((ext_vector_type(4)));
typedef u16 u16x8 __attribute__((ext_vector_type(8)));

// Problem constants (fixed by the reference)
static constexpr int T_TOK = 4096;
static constexpr int HID   = 2048;
static constexpr int INTER = 1024;
static constexpr int NEXP  = 8;
static constexpr int TOPK  = 2;
static constexpr int SLOT_CAP = 9216;   // 8192 real slots + per-expert 128-align pad
static constexpr int NTILE_M = SLOT_CAP / 128;  // 72 flat m-tiles

// meta layout (ints): [0..7] counts, [8..15] offsets, [16] total_aligned,
// [17..24] cursors, [32..32+9216) toklist, [32+9216 .. +8192) slot_of
static constexpr int META_TOK = 32;
static constexpr int META_SLOTOF = 32 + SLOT_CAP;

__device__ __forceinline__ u16 f2bf(float f) {
  u32 u = __builtin_bit_cast(u32, f);
  u32 r = (u + 0x7fffu + ((u >> 16) & 1u)) >> 16;
  return (u16)r;
}
__device__ __forceinline__ float bf2f(u16 h) {
  return __builtin_bit_cast(float, (u32)h << 16);
}

// ---------------- router ----------------
__global__ void router_count(const int* __restrict__ eidx, int* __restrict__ meta) {
  __shared__ int cnt[NEXP];
  const int tid = threadIdx.x;
  if (tid < NEXP) cnt[tid] = 0;
  __syncthreads();
  for (int i = tid; i < T_TOK * TOPK; i += 256) atomicAdd(&cnt[eidx[i]], 1);
  __syncthreads();
  if (tid == 0) {
    int off = 0;
    for (int e = 0; e < NEXP; ++e) {
      int c = cnt[e];
      meta[e] = c;
      meta[8 + e] = off;
      meta[17 + e] = off;            // cursor starts at offset
      off += (c + 127) & ~127;       // 128-aligned region per expert
    }
    meta[16] = off;                  // total aligned slots
  }
}

__global__ void toklist_init(int* __restrict__ meta) {
  const int i = blockIdx.x * 256 + threadIdx.x;
  if (i < SLOT_CAP) meta[META_TOK + i] = 0;   // pad rows use token 0 (valid data, never combined)
}

__global__ void router_assign(const int* __restrict__ eidx, int* __restrict__ meta) {
  const int t = blockIdx.x * 256 + threadIdx.x;
  if (t >= T_TOK) return;
  int* cursors = meta + 17;
  int* toklist = meta + META_TOK;
  int* slot_of = meta + META_SLOTOF;
  for (int k = 0; k < TOPK; ++k) {
    const int e = eidx[t * TOPK + k];
    const int pos = atomicAdd(&cursors[e], 1);
    toklist[pos] = t;
    slot_of[t * TOPK + k] = pos;
  }
}

// ---------------- dequant / cast ----------------
// One thread = 4 packed int32 (4 bytes of nibbles) = 8 output bf16. CPR = chunks per row.
template <int CPR>
__global__ void dequant_k(const int* __restrict__ p, const float* __restrict__ s,
                          u16* __restrict__ w) {
  const int gid = blockIdx.x * 256 + threadIdx.x;
  const int row = gid / CPR;
  const int cid = gid % CPR;
  const int4 pk = *(const int4*)(p + (size_t)gid * 4);
  const float sc = s[(size_t)row * (CPR / 4) + (cid >> 2)];
  int v[4] = {pk.x, pk.y, pk.z, pk.w};
  u16x8 o;
#pragma unroll
  for (int b = 0; b < 4; ++b) {
    o[2 * b]     = f2bf((float)((v[b] & 15) - 8) * sc);
    o[2 * b + 1] = f2bf((float)(((v[b] >> 4) & 15) - 8) * sc);
  }
  *(u16x8*)(w + (size_t)gid * 8) = o;
}

__global__ void cast_x_k(const float* __restrict__ x, u16* __restrict__ xb) {
  const int i = (blockIdx.x * 256 + threadIdx.x) * 8;
  const float4 a = *(const float4*)(x + i);
  const float4 b = *(const float4*)(x + i + 4);
  u16x8 o;
  o[0] = f2bf(a.x); o[1] = f2bf(a.y); o[2] = f2bf(a.z); o[3] = f2bf(a.w);
  o[4] = f2bf(b.x); o[5] = f2bf(b.y); o[6] = f2bf(b.z); o[7] = f2bf(b.w);
  *(u16x8*)(xb + i) = o;
}

// ---------------- grouped GEMM ----------------
// C[slot, n] = sum_k A[row(slot), k] * B[n, k]   (B is K-major / B^T layout)
// 128x128 tile, BK=64, 4 waves (2x2 of 64x64), mfma 16x16x32 bf16.
// FLAT m-tile grid: blockIdx.x = slot-tile over the whole aligned slot space
// (72 tiles); expert found by scanning the 8 region offsets. Dense grid ->
// even CU distribution (R1 lesson: holey grid clustered all work on 64 CUs).
template <int KT, bool GATHER>
__global__ __launch_bounds__(256) void gemm_tile(const u16* __restrict__ A,
                                                 const u16* __restrict__ B,
                                                 u16* __restrict__ C,
                                                 const int* __restrict__ meta) {
  const int slot0 = blockIdx.x * 128;
  if (slot0 >= meta[16]) return;
  int e = 0;
#pragma unroll
  for (int i = 1; i < NEXP; ++i) e += (slot0 >= meta[8 + i]);
  const int n0 = blockIdx.y * 128;
  const int tid = threadIdx.x;

  __shared__ u16 As[128 * 64];
  __shared__ u16 Bs[128 * 64];

  const u16* Be = B + (size_t)e * 2048 * KT;
  const int* toklist = meta + META_TOK;

  // staging sources: chunk c = j*256+tid covers 16B; row = c>>3, col-chunk = tid&7
  const int cofs = (tid & 7) * 8;
  const u16* asrc[4];
  const u16* bsrc[4];
#pragma unroll
  for (int j = 0; j < 4; ++j) {
    const int r = j * 32 + (tid >> 3);
    const int arow = GATHER ? toklist[slot0 + r] : (slot0 + r);
    asrc[j] = A + (size_t)arow * KT + cofs;
    bsrc[j] = Be + (size_t)(n0 + r) * KT + cofs;
  }

  f32x4 acc[4][4];
#pragma unroll
  for (int m = 0; m < 4; ++m)
#pragma unroll
    for (int n = 0; n < 4; ++n) acc[m][n] = (f32x4)0.0f;

  const int lane = tid & 63;
  const int wid = tid >> 6;
  const int wm = (wid >> 1) * 64;
  const int wn = (wid & 1) * 64;
  const int fr = lane & 15;
  const int fk = (lane >> 4) * 8;

  char* AsB = (char*)As;
  char* BsB = (char*)Bs;
  const int ldsoff = tid * 16;

  for (int kk = 0; kk < KT; kk += 64) {
    __syncthreads();
#pragma unroll
    for (int j = 0; j < 4; ++j) {
      __builtin_amdgcn_global_load_lds(
          (const __attribute__((address_space(1))) void*)(asrc[j] + kk),
          (__attribute__((address_space(3))) void*)(AsB + j * 4096 + ldsoff), 16, 0, 0);
      __builtin_amdgcn_global_load_lds(
          (const __attribute__((address_space(1))) void*)(bsrc[j] + kk),
          (__attribute__((address_space(3))) void*)(BsB + j * 4096 + ldsoff), 16, 0, 0);
    }
    __syncthreads();
#pragma unroll
    for (int ks = 0; ks < 2; ++ks) {
      bf16x8 a[4], b[4];
#pragma unroll
      for (int m = 0; m < 4; ++m)
        a[m] = *(const bf16x8*)&As[(wm + m * 16 + fr) * 64 + ks * 32 + fk];
#pragma unroll
      for (int n = 0; n < 4; ++n)
        b[n] = *(const bf16x8*)&Bs[(wn + n * 16 + fr) * 64 + ks * 32 + fk];
#pragma unroll
      for (int m = 0; m < 4; ++m)
#pragma unroll
        for (int n = 0; n < 4; ++n)
          acc[m][n] = __builtin_amdgcn_mfma_f32_16x16x32_bf16(a[m], b[n], acc[m][n], 0, 0, 0);
    }
  }

  // epilogue: C/D layout col=lane&15, row=(lane>>4)*4+j  [m89-verified]
  const int cr = (lane >> 4) * 4;
#pragma unroll
  for (int m = 0; m < 4; ++m)
#pragma unroll
    for (int n = 0; n < 4; ++n)
#pragma unroll
      for (int j = 0; j < 4; ++j) {
        const int row = slot0 + wm + m * 16 + cr + j;
        const int col = n0 + wn + n * 16 + fr;
        C[(size_t)row * 2048 + col] = f2bf(acc[m][n][j]);
      }
}

// ---------------- silu ----------------
__global__ void silu_k(const u16* __restrict__ y13, u16* __restrict__ h,
                       const int* __restrict__ meta) {
  const int idx = blockIdx.x * 256 + threadIdx.x;   // SLOT_CAP * (INTER/8)
  const int slot = idx >> 7;
  if (slot >= meta[16]) return;
  const int pos = (idx & 127) * 8;
  u16x8 g8 = *(const u16x8*)(y13 + (size_t)slot * 2048 + pos);
  u16x8 u8 = *(const u16x8*)(y13 + (size_t)slot * 2048 + 1024 + pos);
  u16x8 o;
#pragma unroll
  for (int j = 0; j < 8; ++j) {
    const float g = bf2f(g8[j]);
    const float u = bf2f(u8[j]);
    const float sg = g / (1.0f + __expf(-g));
    o[j] = f2bf(sg * u);
  }
  *(u16x8*)(h + (size_t)slot * 1024 + pos) = o;
}

// ---------------- combine ----------------
__global__ void combine_k(const u16* __restrict__ yp, const float* __restrict__ ew,
                          const int* __restrict__ meta, float* __restrict__ out) {
  const int idx = blockIdx.x * 256 + threadIdx.x;   // T * (HID/8)
  const int t = idx >> 8;
  const int pos = (idx & 255) * 8;
  const int* slot_of = meta + META_SLOTOF;
  const int s0 = slot_of[t * 2];
  const int s1 = slot_of[t * 2 + 1];
  const float w0 = ew[t * 2];
  const float w1 = ew[t * 2 + 1];
  const u16x8 v0 = *(const u16x8*)(yp + (size_t)s0 * 2048 + pos);
  const u16x8 v1 = *(const u16x8*)(yp + (size_t)s1 * 2048 + pos);
  float* dst = out + (size_t)t * 2048 + pos;
  float4 o0, o1;
  o0.x = w0 * bf2f(v0[0]) + w1 * bf2f(v1[0]);
  o0.y = w0 * bf2f(v0[1]) + w1 * bf2f(v1[1]);
  o0.z = w0 * bf2f(v0[2]) + w1 * bf2f(v1[2]);
  o0.w = w0 * bf2f(v0[3]) + w1 * bf2f(v1[3]);
  o1.x = w0 * bf2f(v0[4]) + w1 * bf2f(v1[4]);
  o1.y = w0 * bf2f(v0[5]) + w1 * bf2f(v1[5]);
  o1.z = w0 * bf2f(v0[6]) + w1 * bf2f(v1[6]);
  o1.w = w0 * bf2f(v0[7]) + w1 * bf2f(v1[7]);
  *(float4*)dst = o0;
  *(float4*)(dst + 4) = o1;
}

// ---------------- launch ----------------
extern "C" void kernel_launch(void* const* d_in, const int* in_sizes, int n_in,
                              void* d_out, int out_size, void* d_ws, size_t ws_size,
                              hipStream_t stream) {
  const float* x    = (const float*)d_in[0];
  const int*   w1   = (const int*)d_in[1];
  const float* w1s  = (const float*)d_in[2];
  const int*   w2   = (const int*)d_in[3];
  const float* w2s  = (const float*)d_in[4];
  const float* ew   = (const float*)d_in[5];
  const int*   eidx = (const int*)d_in[6];
  float* out = (float*)d_out;

  char* ws = (char*)d_ws;
  // ws layout (bytes)
  const size_t OFF_W1B  = 0;           // 8*2048*2048*2  = 67,108,864
  const size_t OFF_W2B  = 67108864;    // 8*2048*1024*2  = 33,554,432
  const size_t OFF_XB   = 100663296;   // 4096*2048*2    = 16,777,216
  const size_t OFF_Y13  = 117440512;   // 9216*2048*2    = 37,748,736 (also yp, reused)
  const size_t OFF_H    = 155189248;   // 9216*1024*2    = 18,874,368
  const size_t OFF_META = 174063616;   // 17440*4        = 69,760
  const size_t NEED     = 174133376;
  if (ws_size < NEED) return;

  u16* W1b  = (u16*)(ws + OFF_W1B);
  u16* W2b  = (u16*)(ws + OFF_W2B);
  u16* xb   = (u16*)(ws + OFF_XB);
  u16* y13  = (u16*)(ws + OFF_Y13);
  u16* hbuf = (u16*)(ws + OFF_H);
  int* meta = (int*)(ws + OFF_META);

  router_count<<<1, 256, 0, stream>>>(eidx, meta);
  toklist_init<<<SLOT_CAP / 256, 256, 0, stream>>>(meta);
  router_assign<<<T_TOK / 256, 256, 0, stream>>>(eidx, meta);

  cast_x_k<<<(T_TOK * HID) / (256 * 8), 256, 0, stream>>>(x, xb);
  // w1: rows = 8*2048 = 16384, chunks/row = (HID/2)/4 = 256
  dequant_k<256><<<16384 * 256 / 256, 256, 0, stream>>>(w1, w1s, W1b);
  // w2: rows = 8*2048 = 16384, chunks/row = (INTER/2)/4 = 128
  dequant_k<128><<<16384 * 128 / 256, 256, 0, stream>>>(w2, w2s, W2b);

  // GEMM1: y13[slot, 0..2048) = x[tok] . W1^T   (K=2048, gather rows); dense 72x16 grid
  gemm_tile<2048, true><<<dim3(NTILE_M, 16), 256, 0, stream>>>(xb, W1b, y13, meta);
  silu_k<<<SLOT_CAP * (INTER / 8) / 256, 256, 0, stream>>>(y13, hbuf, meta);
  // GEMM2: yp[slot, 0..2048) = h[slot] . W2^T   (K=1024, contiguous rows); yp aliases y13
  gemm_tile<1024, false><<<dim3(NTILE_M, 16), 256, 0, stream>>>(hbuf, W2b, y13, meta);

  combine_k<<<(T_TOK * HID) / (256 * 8), 256, 0, stream>>>(y13, ew, meta, out);
}

// Round 3
// 312.061 us; speedup vs baseline: 2.1605x; 1.0462x over previous
//
#include <hip/hip_runtime.h>
#include <cstdint>
#include <cstddef>

typedef unsigned int u32;
typedef unsigned short u16;
typedef __bf16 bf16x8 __attribute__((ext_vector_type(8)));
typedef float f32x4 __attribute__((ext_vector_type(4)));
typedef u16 u16x8 __attribute__((ext_vector_type(8)));

static constexpr int T_TOK = 4096;
static constexpr int HID   = 2048;
static constexpr int INTER = 1024;
static constexpr int NEXP  = 8;
static constexpr int TOPK  = 2;
static constexpr int SLOT_CAP = 9216;          // 8192 real + per-expert 128-align pad
static constexpr int NTILE_M = SLOT_CAP / 128; // 72 m-tiles

static constexpr int META_TOK = 32;
static constexpr int META_SLOTOF = 32 + SLOT_CAP;

__device__ __forceinline__ u16 f2bf(float f) {
  u32 u = __builtin_bit_cast(u32, f);
  u32 r = (u + 0x7fffu + ((u >> 16) & 1u)) >> 16;
  return (u16)r;
}
__device__ __forceinline__ float bf2f(u16 h) {
  return __builtin_bit_cast(float, (u32)h << 16);
}

// ---------------- router ----------------
__global__ void router_count(const int* __restrict__ eidx, int* __restrict__ meta) {
  __shared__ int cnt[NEXP];
  const int tid = threadIdx.x;
  if (tid < NEXP) cnt[tid] = 0;
  __syncthreads();
  for (int i = tid; i < T_TOK * TOPK; i += 256) atomicAdd(&cnt[eidx[i]], 1);
  __syncthreads();
  if (tid == 0) {
    int off = 0;
    for (int e = 0; e < NEXP; ++e) {
      int c = cnt[e];
      meta[e] = c;
      meta[8 + e] = off;
      meta[17 + e] = off;
      off += (c + 127) & ~127;
    }
    meta[16] = off;
  }
}

__global__ void toklist_init(int* __restrict__ meta) {
  const int i = blockIdx.x * 256 + threadIdx.x;
  if (i < SLOT_CAP) meta[META_TOK + i] = 0;   // pad rows use token 0
}

__global__ void router_assign(const int* __restrict__ eidx, int* __restrict__ meta) {
  const int t = blockIdx.x * 256 + threadIdx.x;
  if (t >= T_TOK) return;
  int* cursors = meta + 17;
  int* toklist = meta + META_TOK;
  int* slot_of = meta + META_SLOTOF;
  for (int k = 0; k < TOPK; ++k) {
    const int e = eidx[t * TOPK + k];
    const int pos = atomicAdd(&cursors[e], 1);
    toklist[pos] = t;
    slot_of[t * TOPK + k] = pos;
  }
}

// ---------------- dequant / cast ----------------
template <int CPR>
__global__ void dequant_k(const int* __restrict__ p, const float* __restrict__ s,
                          u16* __restrict__ w) {
  const int gid = blockIdx.x * 256 + threadIdx.x;
  const int row = gid / CPR;
  const int cid = gid % CPR;
  const int4 pk = *(const int4*)(p + (size_t)gid * 4);
  const float sc = s[(size_t)row * (CPR / 4) + (cid >> 2)];
  int v[4] = {pk.x, pk.y, pk.z, pk.w};
  u16x8 o;
#pragma unroll
  for (int b = 0; b < 4; ++b) {
    o[2 * b]     = f2bf((float)((v[b] & 15) - 8) * sc);
    o[2 * b + 1] = f2bf((float)(((v[b] >> 4) & 15) - 8) * sc);
  }
  *(u16x8*)(w + (size_t)gid * 8) = o;
}

__global__ void cast_x_k(const float* __restrict__ x, u16* __restrict__ xb) {
  const int i = (blockIdx.x * 256 + threadIdx.x) * 8;
  const float4 a = *(const float4*)(x + i);
  const float4 b = *(const float4*)(x + i + 4);
  u16x8 o;
  o[0] = f2bf(a.x); o[1] = f2bf(a.y); o[2] = f2bf(a.z); o[3] = f2bf(a.w);
  o[4] = f2bf(b.x); o[5] = f2bf(b.y); o[6] = f2bf(b.z); o[7] = f2bf(b.w);
  *(u16x8*)(xb + i) = o;
}

// ---------------- grouped GEMM, 8-wave phased schedule ----------------
// C[slot, n] = sum_k A[row(slot), k] * B[n, k]  (B is K-major / B^T)
// BM=128 x BN=256, BK=64, 8 waves (2M x 4N), wave-tile 64x64.
// Triple-buffered LDS (3 x 48KB), prefetch depth 2 K-tiles, counted vmcnt(12)
// (never drains to 0 in the main loop). LDS stored as packed 1KB 16x32-bf16
// subtiles with XOR swizzle off^=((off>>8)&3)<<4 (involution); global source
// is pre-swizzled per lane so global_load_lds dest stays linear (m173).
template <int KT, bool GATHER>
__global__ __launch_bounds__(512, 2) void gemm8p(const u16* __restrict__ A,
                                                 const u16* __restrict__ B,
                                                 u16* __restrict__ C,
                                                 const int* __restrict__ meta) {
  static constexpr int NT = KT / 64;          // K-tiles
  static constexpr int BUFB = 49152;          // bytes per buffer (A 16K + B 32K)

  // XCD swizzle: 576 blocks = 8 XCDs x (9 m-tiles x 8 n-tiles)
  const int bid = blockIdx.x;
  const int xcd = bid & 7, q = bid >> 3;
  const int mt = xcd * 9 + (q >> 3);
  const int nt = q & 7;
  const int slot0 = mt * 128;
  if (slot0 >= meta[16]) return;
  int e = 0;
#pragma unroll
  for (int i = 1; i < NEXP; ++i) e += (slot0 >= meta[8 + i]);
  const int n0 = nt * 256;
  const int tid = threadIdx.x;

  __shared__ u16 lds[3 * (BUFB / 2)];
  char* ldsB = (char*)lds;

  const u16* Be = B + (size_t)e * 2048 * KT;
  const int* toklist = meta + META_TOK;

  // --- staging source precompute: 2 A-chunks + 4 B-chunks of 16B per thread ---
  // dest linear byte L -> subtile S=L>>10, o_sw=L&1023; o_in = o_sw ^ swz;
  // row r = (S>>1)*16 + (o_in>>6), col byte = (S&1)*64 + (o_in&63).
  const u16* asrc[2];
  const u16* bsrc[4];
#pragma unroll
  for (int j = 0; j < 2; ++j) {
    const int L = j * 8192 + tid * 16;
    const int S = L >> 10;
    int o = L & 1023;
    o ^= ((o >> 8) & 3) << 4;
    const int r = (S >> 1) * 16 + (o >> 6);
    const int cb = (S & 1) * 64 + (o & 63);
    const int arow = GATHER ? toklist[slot0 + r] : (slot0 + r);
    asrc[j] = A + (size_t)arow * KT + (cb >> 1);
  }
#pragma unroll
  for (int j = 0; j < 4; ++j) {
    const int L = j * 8192 + tid * 16;
    const int S = L >> 10;
    int o = L & 1023;
    o ^= ((o >> 8) & 3) << 4;
    const int r = (S >> 1) * 16 + (o >> 6);
    const int cb = (S & 1) * 64 + (o & 63);
    bsrc[j] = Be + (size_t)(n0 + r) * KT + (cb >> 1);
  }

#define STAGE(kt_, buf_)                                                              \
  do {                                                                                \
    char* dA_ = ldsB + (buf_) * BUFB;                                                 \
    char* dB_ = dA_ + 16384;                                                          \
    _Pragma("unroll") for (int j = 0; j < 2; ++j)                                     \
        __builtin_amdgcn_global_load_lds(                                             \
            (const __attribute__((address_space(1))) void*)(asrc[j] + (kt_) * 64),    \
            (__attribute__((address_space(3))) void*)(dA_ + j * 8192 + tid * 16),     \
            16, 0, 0);                                                                \
    _Pragma("unroll") for (int j = 0; j < 4; ++j)                                     \
        __builtin_amdgcn_global_load_lds(                                             \
            (const __attribute__((address_space(1))) void*)(bsrc[j] + (kt_) * 64),    \
            (__attribute__((address_space(3))) void*)(dB_ + j * 8192 + tid * 16),     \
            16, 0, 0);                                                                \
  } while (0)

  // --- fragment LDS byte offsets (swizzled reads) ---
  const int lane = tid & 63;
  const int wid = tid >> 6;
  const int wm = (wid >> 2) * 64;   // 2 M-groups
  const int wn = (wid & 3) * 64;    // 4 N-groups
  const int fr = lane & 15;
  const int qq = lane >> 4;
  const int swz = (qq * 16) ^ (((fr >> 2) & 3) << 4);

  int aoffb[4][2], boffb[4][2];
#pragma unroll
  for (int m = 0; m < 4; ++m)
#pragma unroll
    for (int ks = 0; ks < 2; ++ks)
      aoffb[m][ks] = ((wm >> 4) + m) * 2048 + ks * 1024 + fr * 64 + swz;
#pragma unroll
  for (int n = 0; n < 4; ++n)
#pragma unroll
    for (int ks = 0; ks < 2; ++ks)
      boffb[n][ks] = 16384 + ((wn >> 4) + n) * 2048 + ks * 1024 + fr * 64 + swz;

  f32x4 acc[4][4];
#pragma unroll
  for (int m = 0; m < 4; ++m)
#pragma unroll
    for (int n = 0; n < 4; ++n) acc[m][n] = (f32x4)0.0f;

  // prologue: stage tiles 0,1 (12 loads in flight)
  STAGE(0, 0);
  STAGE(1, 1);

#pragma unroll 1
  for (int kt = 0; kt < NT; ++kt) {
    const int cur = kt % 3;
    if (kt + 2 < NT) {
      STAGE(kt + 2, (kt + 2) % 3);
      asm volatile("s_waitcnt vmcnt(12)" ::: "memory");   // keep 2 tiles in flight
    } else if (kt + 1 < NT) {
      asm volatile("s_waitcnt vmcnt(6)" ::: "memory");
    } else {
      asm volatile("s_waitcnt vmcnt(0)" ::: "memory");
    }
    __builtin_amdgcn_s_barrier();           // buffer `cur` certified landed (all waves)
    __builtin_amdgcn_sched_barrier(0);
    asm volatile("" ::: "memory");

    const char* bufc = ldsB + cur * BUFB;

    // ---- phase 0: read A (8) + B[n0,n1] (4); MFMA quadrant n0-1 (16) ----
    bf16x8 af[4][2];
#pragma unroll
    for (int m = 0; m < 4; ++m)
#pragma unroll
      for (int ks = 0; ks < 2; ++ks)
        af[m][ks] = *(const bf16x8*)(bufc + aoffb[m][ks]);
    bf16x8 bf0[2][2];
#pragma unroll
    for (int n = 0; n < 2; ++n)
#pragma unroll
      for (int ks = 0; ks < 2; ++ks)
        bf0[n][ks] = *(const bf16x8*)(bufc + boffb[n][ks]);
    __builtin_amdgcn_s_setprio(1);
#pragma unroll
    for (int m = 0; m < 4; ++m)
#pragma unroll
      for (int n = 0; n < 2; ++n)
#pragma unroll
        for (int ks = 0; ks < 2; ++ks)
          acc[m][n] = __builtin_amdgcn_mfma_f32_16x16x32_bf16(af[m][ks], bf0[n][ks], acc[m][n], 0, 0, 0);
    __builtin_amdgcn_s_setprio(0);
    __builtin_amdgcn_s_barrier();
    asm volatile("" ::: "memory");

    // ---- phase 1: read B[n2,n3] (4); MFMA quadrant n2-3 (16) ----
    bf16x8 bf1[2][2];
#pragma unroll
    for (int n = 0; n < 2; ++n)
#pragma unroll
      for (int ks = 0; ks < 2; ++ks)
        bf1[n][ks] = *(const bf16x8*)(bufc + boffb[2 + n][ks]);
    __builtin_amdgcn_s_setprio(1);
#pragma unroll
    for (int m = 0; m < 4; ++m)
#pragma unroll
      for (int n = 0; n < 2; ++n)
#pragma unroll
        for (int ks = 0; ks < 2; ++ks)
          acc[m][2 + n] = __builtin_amdgcn_mfma_f32_16x16x32_bf16(af[m][ks], bf1[n][ks], acc[m][2 + n], 0, 0, 0);
    __builtin_amdgcn_s_setprio(0);
    __builtin_amdgcn_s_barrier();
    asm volatile("" ::: "memory");
  }
#undef STAGE

  // epilogue: C/D layout col=lane&15, row=(lane>>4)*4+j
  const int cr = qq * 4;
#pragma unroll
  for (int m = 0; m < 4; ++m)
#pragma unroll
    for (int n = 0; n < 4; ++n)
#pragma unroll
      for (int j = 0; j < 4; ++j) {
        const int row = slot0 + wm + m * 16 + cr + j;
        const int col = n0 + wn + n * 16 + fr;
        C[(size_t)row * 2048 + col] = f2bf(acc[m][n][j]);
      }
}

// ---------------- silu ----------------
__global__ void silu_k(const u16* __restrict__ y13, u16* __restrict__ h,
                       const int* __restrict__ meta) {
  const int idx = blockIdx.x * 256 + threadIdx.x;
  const int slot = idx >> 7;
  if (slot >= meta[16]) return;
  const int pos = (idx & 127) * 8;
  u16x8 g8 = *(const u16x8*)(y13 + (size_t)slot * 2048 + pos);
  u16x8 u8 = *(const u16x8*)(y13 + (size_t)slot * 2048 + 1024 + pos);
  u16x8 o;
#pragma unroll
  for (int j = 0; j < 8; ++j) {
    const float g = bf2f(g8[j]);
    const float u = bf2f(u8[j]);
    const float sg = g / (1.0f + __expf(-g));
    o[j] = f2bf(sg * u);
  }
  *(u16x8*)(h + (size_t)slot * 1024 + pos) = o;
}

// ---------------- combine ----------------
__global__ void combine_k(const u16* __restrict__ yp, const float* __restrict__ ew,
                          const int* __restrict__ meta, float* __restrict__ out) {
  const int idx = blockIdx.x * 256 + threadIdx.x;
  const int t = idx >> 8;
  const int pos = (idx & 255) * 8;
  const int* slot_of = meta + META_SLOTOF;
  const int s0 = slot_of[t * 2];
  const int s1 = slot_of[t * 2 + 1];
  const float w0 = ew[t * 2];
  const float w1 = ew[t * 2 + 1];
  const u16x8 v0 = *(const u16x8*)(yp + (size_t)s0 * 2048 + pos);
  const u16x8 v1 = *(const u16x8*)(yp + (size_t)s1 * 2048 + pos);
  float* dst = out + (size_t)t * 2048 + pos;
  float4 o0, o1;
  o0.x = w0 * bf2f(v0[0]) + w1 * bf2f(v1[0]);
  o0.y = w0 * bf2f(v0[1]) + w1 * bf2f(v1[1]);
  o0.z = w0 * bf2f(v0[2]) + w1 * bf2f(v1[2]);
  o0.w = w0 * bf2f(v0[3]) + w1 * bf2f(v1[3]);
  o1.x = w0 * bf2f(v0[4]) + w1 * bf2f(v1[4]);
  o1.y = w0 * bf2f(v0[5]) + w1 * bf2f(v1[5]);
  o1.z = w0 * bf2f(v0[6]) + w1 * bf2f(v1[6]);
  o1.w = w0 * bf2f(v0[7]) + w1 * bf2f(v1[7]);
  *(float4*)dst = o0;
  *(float4*)(dst + 4) = o1;
}

// ---------------- launch ----------------
extern "C" void kernel_launch(void* const* d_in, const int* in_sizes, int n_in,
                              void* d_out, int out_size, void* d_ws, size_t ws_size,
                              hipStream_t stream) {
  const float* x    = (const float*)d_in[0];
  const int*   w1   = (const int*)d_in[1];
  const float* w1s  = (const float*)d_in[2];
  const int*   w2   = (const int*)d_in[3];
  const float* w2s  = (const float*)d_in[4];
  const float* ew   = (const float*)d_in[5];
  const int*   eidx = (const int*)d_in[6];
  float* out = (float*)d_out;

  char* ws = (char*)d_ws;
  const size_t OFF_W1B  = 0;           // 8*2048*2048*2  = 67,108,864
  const size_t OFF_W2B  = 67108864;    // 8*2048*1024*2  = 33,554,432
  const size_t OFF_XB   = 100663296;   // 4096*2048*2    = 16,777,216
  const size_t OFF_Y13  = 117440512;   // 9216*2048*2    = 37,748,736 (also yp, reused)
  const size_t OFF_H    = 155189248;   // 9216*1024*2    = 18,874,368
  const size_t OFF_META = 174063616;   // 17440*4        = 69,760
  const size_t NEED     = 174133376;
  if (ws_size < NEED) return;

  u16* W1b  = (u16*)(ws + OFF_W1B);
  u16* W2b  = (u16*)(ws + OFF_W2B);
  u16* xb   = (u16*)(ws + OFF_XB);
  u16* y13  = (u16*)(ws + OFF_Y13);
  u16* hbuf = (u16*)(ws + OFF_H);
  int* meta = (int*)(ws + OFF_META);

  router_count<<<1, 256, 0, stream>>>(eidx, meta);
  toklist_init<<<SLOT_CAP / 256, 256, 0, stream>>>(meta);
  router_assign<<<T_TOK / 256, 256, 0, stream>>>(eidx, meta);

  cast_x_k<<<(T_TOK * HID) / (256 * 8), 256, 0, stream>>>(x, xb);
  dequant_k<256><<<16384 * 256 / 256, 256, 0, stream>>>(w1, w1s, W1b);
  dequant_k<128><<<16384 * 128 / 256, 256, 0, stream>>>(w2, w2s, W2b);

  // GEMM1: y13[slot, 0..2048) = x[tok] . W1^T  (K=2048, gather); 72x8=576 blocks
  gemm8p<2048, true><<<NTILE_M * 8, 512, 0, stream>>>(xb, W1b, y13, meta);
  silu_k<<<SLOT_CAP * (INTER / 8) / 256, 256, 0, stream>>>(y13, hbuf, meta);
  // GEMM2: yp[slot, 0..2048) = h[slot] . W2^T  (K=1024, contiguous); yp aliases y13
  gemm8p<1024, false><<<NTILE_M * 8, 512, 0, stream>>>(hbuf, W2b, y13, meta);

  combine_k<<<(T_TOK * HID) / (256 * 8), 256, 0, stream>>>(y13, ew, meta, out);
}